// Round 5
// baseline (185.505 us; speedup 1.0000x reference)
//
#include <hip/hip_runtime.h>
#include <math.h>

// PCE basis expansion: Phi[n,b] = prod_j polyval(xn[n,j], idxset[b,j])
// D=50, P=2. Output 32768x1326 fp32 = 174 MB -> write-BW floor ~26 us.
//
// R6: 128B-ALIGNED full-line stores (discriminator probe).
// Every prior version (R0-R5) stored at row-granular addresses; rows are
// 5304 B (5304 % 128 = 56), so EVERY wave store instruction partially
// covered its first/last cache line. If gfx950 L2 fetches on partial-line
// write-miss, pce pays a hidden ~174 MB RFO (-> ~2x its write floor), and
// that shared flaw explains why conflict/width changes were all null.
// Fix: flatten each block's 16 rows = 21216 floats = 84864 B = EXACTLY 663
// cache lines (block base = blk*84864 % 128 == 0). Store float4 slot
// f = tid + 256*s -> each wave store covers 8 whole lines, zero partial.
// A float4 never straddles a row-PAIR (2652 % 4 == 0), so a per-pair
// descriptor table (2652 packed ints, built once/block in LDS from the
// R3/R4/R5-verified col_desc; row-in-pair folded as +RS bias; pair bias
// p*240 added at use, max offset 7*240+239 = 1919 < 1920 table floats)
// maps each element to its two factors. Table layout + factor math are
// byte-identical to R5 -> absmax stays 0.
// Column -> factors closed form (verified, absmax 0):
//   c==0 -> 1 ; 1<=c<=50 -> rev[c-1] ; c>=51: t=c-51, q=trinv(t), s=t-T(q);
//   s==q -> H2[q] else rev[s]*rev[q],  rev[k]=H1(x_{49-k}).

#define DD     50
#define NBASIS 1326
#define BN     16
#define BLOCK  256
#define RS     120            // LDS row stride in floats
#define ONE    56             // slot holding 1.0 (padk max is 55)
#define H2OFF  64             // padded H2 base; max off = 64+55 = 119 < RS
#define NDESC  2652           // floats per row-pair = desc table entries
#define GF4    5304           // float4s per 16-row group (21216/4)
#define FULLS  20             // full emit passes (20*256 = 5120)
#define TAIL   184            // 5304 - 5120

__device__ __forceinline__ int padk(int k) { return k + (k >> 3); }

// col -> (off0 | off1<<8), offsets into the padded per-row table (<= 239)
__device__ __forceinline__ int col_desc(int c) {
    if (c == 0) return ONE | (ONE << 8);
    if (c <= DD) return padk(c - 1) | (ONE << 8);      // rev[c-1] * 1.0
    int t = c - (DD + 1);                              // order-2 block index
    int q = (int)((sqrtf((float)(8 * t + 1)) - 1.0f) * 0.5f);
    while ((q + 1) * (q + 2) / 2 <= t) ++q;            // exact fix-up
    while (q * (q + 1) / 2 > t) --q;
    int s = t - q * (q + 1) / 2;                       // position within run q
    if (s == q) return (H2OFF + padk(q)) | (ONE << 8); // H2(x_{49-q}) * 1.0
    return padk(s) | (padk(q) << 8);                   // rev[s] * rev[q]
}

__global__ __launch_bounds__(BLOCK) void pce_kernel(
    const float* __restrict__ x, const float* __restrict__ mean,
    const float* __restrict__ var, const float* __restrict__ basis,
    float* __restrict__ out, int n)
{
    __shared__ float T[BN * RS];          // 1920 floats = 7.7 KB (rows flat)
    __shared__ int   Dsc[NDESC];          // 10.6 KB packed descriptors
    const int tid  = threadIdx.x;
    const int row0 = blockIdx.x * BN;

    // Hermite basis coefficients (broadcast loads, cached)
    float b10 = basis[3], b11 = basis[4], b12 = basis[5];
    float b20 = basis[6], b21 = basis[7], b22 = basis[8];

    // ---- Build per-pair descriptor table (once per block) ----
    for (int e = tid; e < NDESC; e += BLOCK) {
        int rf  = (e >= NBASIS) ? 1 : 0;              // row-in-pair
        int col = e - rf * NBASIS;
        Dsc[e] = col_desc(col) + rf * (RS | (RS << 8)); // bias both fields
    }

    // ---- Stage padded reversed H1/H2 tables (coalesced x reads) ----
    for (int i = tid; i < BN * DD; i += BLOCK) {
        int r = i / DD, c = i - r * DD;
        float xv = (x[(size_t)(row0 + r) * DD + c] - mean[c]) / var[c];
        float x2 = xv * xv;
        int k  = (DD - 1) - c;                        // reversed dim index
        int pk = padk(k);                             // pad: breaks stride-4
        T[r * RS + pk]         = b10 + b11 * xv + b12 * x2;   // H1
        T[r * RS + H2OFF + pk] = b20 + b21 * xv + b22 * x2;   // H2
    }
    if (tid < BN) T[tid * RS + ONE] = 1.0f;           // identity factor
    __syncthreads();

    // ---- Emit: float4 slot f = tid + 256*s over the flat 16-row group.
    //      Every wave store = 1024 B at 128B-aligned base -> 8 full lines.
    float4* ob = (float4*)(out + (size_t)blockIdx.x * (BN * NBASIS));
    int rm = tid;          // f mod 663  (float4 index within row-pair)
    int pb = 0;            // pairIdx * 2*RS (table bias for this pair)
    #pragma unroll
    for (int s = 0; s < FULLS; ++s) {
        const int4 d4 = *(const int4*)&Dsc[4 * rm];   // 16B-aligned b128
        float4 w;
        w.x = T[(d4.x & 0xff) + pb] * T[((d4.x >> 8) & 0xff) + pb];
        w.y = T[(d4.y & 0xff) + pb] * T[((d4.y >> 8) & 0xff) + pb];
        w.z = T[(d4.z & 0xff) + pb] * T[((d4.z >> 8) & 0xff) + pb];
        w.w = T[(d4.w & 0xff) + pb] * T[((d4.w >> 8) & 0xff) + pb];
        ob[tid + BLOCK * s] = w;
        rm += BLOCK;
        if (rm >= 663) { rm -= 663; pb += 2 * RS; }   // next row-pair
    }
    if (tid < TAIL) {                                 // slots 5120..5303
        const int4 d4 = *(const int4*)&Dsc[4 * rm];
        float4 w;
        w.x = T[(d4.x & 0xff) + pb] * T[((d4.x >> 8) & 0xff) + pb];
        w.y = T[(d4.y & 0xff) + pb] * T[((d4.y >> 8) & 0xff) + pb];
        w.z = T[(d4.z & 0xff) + pb] * T[((d4.z >> 8) & 0xff) + pb];
        w.w = T[(d4.w & 0xff) + pb] * T[((d4.w >> 8) & 0xff) + pb];
        ob[tid + BLOCK * FULLS] = w;
    }
}

extern "C" void kernel_launch(void* const* d_in, const int* in_sizes, int n_in,
                              void* d_out, int out_size, void* d_ws, size_t ws_size,
                              hipStream_t stream) {
    const float* x     = (const float*)d_in[0];
    const float* mean  = (const float*)d_in[1];
    const float* var   = (const float*)d_in[2];
    const float* basis = (const float*)d_in[3];
    float* out = (float*)d_out;

    const int d = in_sizes[1];          // 50
    const int n = in_sizes[0] / d;      // 32768

    (void)d_ws; (void)ws_size;          // workspace intentionally unused

    pce_kernel<<<(n + BN - 1) / BN, BLOCK, 0, stream>>>(x, mean, var, basis, out, n);
}